// Round 3
// baseline (424.247 us; speedup 1.0000x reference)
//
#include <hip/hip_runtime.h>
#include <math.h>

#define N 8192
#define T 8192
#define RB 32
#define CB 32
#define HID 100
#define DIO (RB*CB)

#define RPB 8                 // rows per k_blocksum block (128 KB contiguous read)
#define BS_BLOCKS (N / RPB)   // 1024 blocks
#define K1BLOCKS 32
#define KCHUNK (DIO/K1BLOCKS)

// K0: zero the accumulator + segment boundaries from sorted ids.
__global__ void k_bounds(const int* __restrict__ row_ids, const int* __restrict__ col_ids,
                         int* __restrict__ rc, int* __restrict__ cc, float* __restrict__ blk) {
    int tid = blockIdx.x * blockDim.x + threadIdx.x;
    int stride = gridDim.x * blockDim.x;
    for (int i = tid; i < DIO; i += stride) blk[i] = 0.f;
    for (int i = tid; i < N; i += stride) {
        int a = row_ids[i];
        int b = (i + 1 < N) ? row_ids[i + 1] : RB;
        for (int k = a + 1; k <= b; ++k) rc[k] = i + 1;
        if (i == 0) { for (int k = 0; k <= a; ++k) rc[k] = 0; }
    }
    for (int i = tid; i < T; i += stride) {
        int a = col_ids[i];
        int b = (i + 1 < T) ? col_ids[i + 1] : CB;
        for (int k = a + 1; k <= b; ++k) cc[k] = i + 1;
        if (i == 0) { for (int k = 0; k <= a; ++k) cc[k] = 0; }
    }
}

// Flush: reduce per-thread float4 accumulators into blk[rs][*] using a
// wave-level segmented suffix-sum (col segments are monotonic across lanes),
// so only segment-boundary lanes issue (collision-free) global atomics.
__device__ __forceinline__ void flush_seg(float4* acc, const int4* __restrict__ col_ids4,
                                          int t, int rs, float* __restrict__ blk) {
    const int lane = t & 63;
    #pragma unroll
    for (int j = 0; j < 8; ++j) {
        int4 cs = col_ids4[t + 256 * j];      // L2-resident (32 KB total)
        int key = cs.x;
        float v;
        if (cs.w == key) {                    // whole float4 in one col segment (common)
            v = acc[j].x + acc[j].y + acc[j].z + acc[j].w;
        } else {                              // boundary inside the float4 (rare lanes)
            v = acc[j].x;
            if (cs.y == key) v += acc[j].y; else atomicAdd(&blk[rs * CB + cs.y], acc[j].y);
            if (cs.z == key) v += acc[j].z; else atomicAdd(&blk[rs * CB + cs.z], acc[j].z);
            if (cs.w == key) v += acc[j].w; else atomicAdd(&blk[rs * CB + cs.w], acc[j].w);
        }
        // segmented suffix-sum across the wave; exact because keys are sorted
        #pragma unroll
        for (int d = 1; d < 64; d <<= 1) {
            float vv = __shfl_down(v, d, 64);
            int   kk = __shfl_down(key, d, 64);
            if (lane + d < 64 && kk == key) v += vv;
        }
        int kprev = __shfl_up(key, 1, 64);
        if (lane == 0 || kprev != key)
            atomicAdd(&blk[rs * CB + key], v);
        acc[j] = make_float4(0.f, 0.f, 0.f, 0.f);
    }
}

// K1: one contiguous pass over X. Block b streams rows [8b, 8b+8) x all 8192
// cols (128 KB contiguous). 8 independent float4 loads in flight per lane.
// No LDS, no block-level sync.
__global__ __launch_bounds__(256) void k_blocksum(const float* __restrict__ X,
        const int* __restrict__ row_ids, const int* __restrict__ col_ids,
        float* __restrict__ blk) {
    const int t = threadIdx.x;
    const int b = blockIdx.x;
    const int r0 = b * RPB;
    const float4* __restrict__ X4 = (const float4*)X;
    const int4*   __restrict__ C4 = (const int4*)col_ids;

    float4 acc[8];
    #pragma unroll
    for (int j = 0; j < 8; ++j) acc[j] = make_float4(0.f, 0.f, 0.f, 0.f);

    const int4* rid4 = (const int4*)(row_ids + r0);
    int4 ra = rid4[0], rb = rid4[1];

    if (ra.x == rb.w) {
        // fast path: all 8 rows in one row segment (~97% of blocks)
        #pragma unroll
        for (int r = 0; r < RPB; ++r) {
            const float4* __restrict__ row = X4 + (size_t)(r0 + r) * (T / 4);
            #pragma unroll
            for (int j = 0; j < 8; ++j) {
                float4 x = row[t + 256 * j];
                acc[j].x += x.x; acc[j].y += x.y; acc[j].z += x.z; acc[j].w += x.w;
            }
        }
        flush_seg(acc, C4, t, ra.x, blk);
    } else {
        int rseg[RPB] = {ra.x, ra.y, ra.z, ra.w, rb.x, rb.y, rb.z, rb.w};
        int cur = rseg[0];
        for (int r = 0; r < RPB; ++r) {
            if (rseg[r] != cur) { flush_seg(acc, C4, t, cur, blk); cur = rseg[r]; }
            const float4* __restrict__ row = X4 + (size_t)(r0 + r) * (T / 4);
            #pragma unroll
            for (int j = 0; j < 8; ++j) {
                float4 x = row[t + 256 * j];
                acc[j].x += x.x; acc[j].y += x.y; acc[j].z += x.z; acc[j].w += x.w;
            }
        }
        flush_seg(acc, C4, t, cur, blk);
    }
}

// K2a: layer-1 partials, K-parallel over 32 blocks.
__global__ __launch_bounds__(128) void k_mlp1(const float* __restrict__ blk,
        const int* __restrict__ rc, const int* __restrict__ cc,
        const float* __restrict__ W1, float* __restrict__ part1) {
    __shared__ float xs[KCHUNK];
    const int b = blockIdx.x, t = threadIdx.x;
    const int k0 = b * KCHUNK;
    if (t < KCHUNK) {
        int k = k0 + t;
        int r = k >> 5, c = k & 31;
        float cnt = fmaxf((float)(rc[r + 1] - rc[r]) * (float)(cc[c + 1] - cc[c]), 1.0f);
        xs[t] = blk[k] / cnt;
    }
    __syncthreads();
    if (t < HID) {
        float s = 0.f;
        #pragma unroll 8
        for (int kk = 0; kk < KCHUNK; ++kk)
            s += xs[kk] * W1[(size_t)(k0 + kk) * HID + t];
        part1[b * HID + t] = s;
    }
}

// K2b: reduce partials + relu, layer 2 + relu; emit cumsum outputs.
__global__ __launch_bounds__(128) void k_mlp2(const float* __restrict__ part1,
        const float* __restrict__ b1, const float* __restrict__ W2,
        const float* __restrict__ b2, const int* __restrict__ rc,
        const int* __restrict__ cc, float* __restrict__ h2out,
        float* __restrict__ out) {
    __shared__ float h1[HID];
    const int t = threadIdx.x;
    if (t < HID) {
        float s = b1[t];
        #pragma unroll 8
        for (int b = 0; b < K1BLOCKS; ++b) s += part1[b * HID + t];
        h1[t] = fmaxf(s, 0.f);
    }
    __syncthreads();
    if (t < HID) {
        float s = b2[t];
        #pragma unroll 4
        for (int k = 0; k < HID; ++k) s += h1[k] * W2[k * HID + t];
        h2out[t] = fmaxf(s, 0.f);
    }
    if (t < RB + 1) out[DIO + t] = (float)rc[t];
    if (t < CB + 1) out[DIO + RB + 1 + t] = (float)cc[t];
}

// K2c: layer 3 + sigmoid, output-parallel over 8 blocks.
__global__ __launch_bounds__(128) void k_mlp3(const float* __restrict__ h2,
        const float* __restrict__ W3, const float* __restrict__ b3,
        float* __restrict__ out) {
    __shared__ float h[HID];
    const int t = threadIdx.x;
    if (t < HID) h[t] = h2[t];
    __syncthreads();
    const int o = blockIdx.x * 128 + t;
    float s = b3[o];
    #pragma unroll 4
    for (int k = 0; k < HID; ++k) s += h[k] * W3[k * DIO + o];
    out[o] = 1.f / (1.f + expf(-s));
}

extern "C" void kernel_launch(void* const* d_in, const int* in_sizes, int n_in,
                              void* d_out, int out_size, void* d_ws, size_t ws_size,
                              hipStream_t stream) {
    const float* X       = (const float*)d_in[0];
    const int*   row_ids = (const int*)  d_in[1];
    const int*   col_ids = (const int*)  d_in[2];
    const float* W1      = (const float*)d_in[3];
    const float* b1      = (const float*)d_in[4];
    const float* W2      = (const float*)d_in[5];
    const float* b2      = (const float*)d_in[6];
    const float* W3      = (const float*)d_in[7];
    const float* b3      = (const float*)d_in[8];
    float* out = (float*)d_out;

    float* blk   = (float*)d_ws;              // 1024
    float* part1 = blk + DIO;                 // 32*100
    float* h2    = part1 + K1BLOCKS * HID;    // 100
    int*   rc    = (int*)(h2 + HID);          // 33
    int*   cc    = rc + (RB + 1);             // 33

    k_bounds<<<16, 256, 0, stream>>>(row_ids, col_ids, rc, cc, blk);
    k_blocksum<<<BS_BLOCKS, 256, 0, stream>>>(X, row_ids, col_ids, blk);
    k_mlp1<<<K1BLOCKS, 128, 0, stream>>>(blk, rc, cc, W1, part1);
    k_mlp2<<<1, 128, 0, stream>>>(part1, b1, W2, b2, rc, cc, h2, out);
    k_mlp3<<<DIO / 128, 128, 0, stream>>>(h2, W3, b3, out);
}